// Round 3
// baseline (1084.312 us; speedup 1.0000x reference)
//
#include <hip/hip_runtime.h>
#include <hip/hip_bf16.h>

// GCNConvDiagDGL: out = segment_sum( (features*W)[src], dst, N )
// N=100000, E=1600000, D=64, fp32.
//
// Round 2 -> 3: node-granular counting sort (107 MB write amplification on a
// 6.4 MB payload) replaced by bucket-granular binning + LDS scatter-add:
//   1. hist of dst>>7 (K=782 buckets of 128 nodes), LDS-staged
//   2. one-block scan of K counts -> base[], cursor[]
//   3. partition: packed 4B word (src<<7 | dst&127) appended to bucket region
//      (consecutive cursor slots are temporally adjacent -> lines fill)
//   4. accumulate: 1 block/bucket, acc[128][64] fp32 in 32KB LDS,
//      1 wave/edge (lane=feature), ds_add_f32 LDS atomics, epilogue *W +
//      coalesced float4 store. Output written exactly once.

#define D 64
#define NPB 128        // nodes per bucket
#define NPB_BITS 7
#define KMAX 1024      // max buckets supported by hist/scan

// ---------------- block-wide exclusive scan helper ----------------
template <int NW>
__device__ inline int block_excl_scan(int val, int tid, int* lds_wsum, int* total) {
    const int lane = tid & 63;
    const int wid  = tid >> 6;
    int v = val;
#pragma unroll
    for (int d = 1; d < 64; d <<= 1) {
        int t = __shfl_up(v, d);
        if (lane >= d) v += t;
    }
    if (lane == 63) lds_wsum[wid] = v;
    __syncthreads();
    if (wid == 0) {
        int s = (lane < NW) ? lds_wsum[lane] : 0;
#pragma unroll
        for (int d = 1; d < NW; d <<= 1) {
            int t = __shfl_up(s, d);
            if (lane >= d) s += t;
        }
        if (lane < NW) lds_wsum[lane] = s;
    }
    __syncthreads();
    const int base = wid ? lds_wsum[wid - 1] : 0;
    *total = lds_wsum[NW - 1];
    return base + v - val;  // exclusive
}

// ---------------- 1. bucket histogram (LDS-staged) ----------------
__global__ void __launch_bounds__(256) hist_kernel(const int* __restrict__ dst,
                                                   int* __restrict__ counts,
                                                   int n_edges, int K) {
    __shared__ int h[KMAX];
    for (int i = threadIdx.x; i < K; i += 256) h[i] = 0;
    __syncthreads();
    for (int e = blockIdx.x * 256 + threadIdx.x; e < n_edges; e += gridDim.x * 256)
        atomicAdd(&h[dst[e] >> NPB_BITS], 1);
    __syncthreads();
    for (int i = threadIdx.x; i < K; i += 256)
        if (h[i]) atomicAdd(&counts[i], h[i]);
}

// ---------------- 2. scan K bucket counts (single block) ----------------
__global__ void __launch_bounds__(1024) scan_kernel(const int* __restrict__ counts,
                                                    int* __restrict__ base,
                                                    int* __restrict__ cursor, int K) {
    __shared__ int wsum[16];
    const int tid = threadIdx.x;
    const int v = (tid < K) ? counts[tid] : 0;
    int total;
    const int ex = block_excl_scan<16>(v, tid, wsum, &total);
    if (tid < K) { base[tid] = ex; cursor[tid] = ex; }
    if (tid == 0) base[K] = total;
}

// ---------------- 3. partition edges into buckets (packed 4B) ----------------
__global__ void __launch_bounds__(256) part_kernel(const int* __restrict__ src,
                                                   const int* __restrict__ dst,
                                                   int* __restrict__ cursor,
                                                   int* __restrict__ packed,
                                                   int n_edges) {
    const int e = blockIdx.x * 256 + threadIdx.x;
    if (e >= n_edges) return;
    const int d = dst[e];
    const int b = d >> NPB_BITS;
    const int pos = atomicAdd(&cursor[b], 1);
    packed[pos] = (src[e] << NPB_BITS) | (d & (NPB - 1));
}

// ---------------- 4. per-bucket LDS accumulate ----------------
__global__ void __launch_bounds__(512) accum_kernel(const float* __restrict__ feat,
                                                    const float* __restrict__ W,
                                                    const int* __restrict__ base,
                                                    const int* __restrict__ packed,
                                                    float* __restrict__ out,
                                                    int n_nodes) {
    __shared__ float acc[NPB * D];  // 32 KB
    const int tid = threadIdx.x;
    for (int i = tid; i < NPB * D; i += 512) acc[i] = 0.0f;
    __syncthreads();

    const int b   = blockIdx.x;
    const int beg = base[b];
    const int end = base[b + 1];
    const int wid  = tid >> 6;
    const int lane = tid & 63;

    // contiguous chunk per wave, 4x unrolled
    const int cnt   = end - beg;
    const int chunk = (cnt + 7) >> 3;
    int i    = beg + wid * chunk;
    int iend = i + chunk;
    if (iend > end) iend = end;

    for (; i + 4 <= iend; i += 4) {
        const int p0 = packed[i + 0];
        const int p1 = packed[i + 1];
        const int p2 = packed[i + 2];
        const int p3 = packed[i + 3];
        const float f0 = feat[(p0 >> NPB_BITS) * D + lane];
        const float f1 = feat[(p1 >> NPB_BITS) * D + lane];
        const float f2 = feat[(p2 >> NPB_BITS) * D + lane];
        const float f3 = feat[(p3 >> NPB_BITS) * D + lane];
        atomicAdd(&acc[(p0 & (NPB - 1)) * D + lane], f0);
        atomicAdd(&acc[(p1 & (NPB - 1)) * D + lane], f1);
        atomicAdd(&acc[(p2 & (NPB - 1)) * D + lane], f2);
        atomicAdd(&acc[(p3 & (NPB - 1)) * D + lane], f3);
    }
    for (; i < iend; ++i) {
        const int p = packed[i];
        atomicAdd(&acc[(p & (NPB - 1)) * D + lane], feat[(p >> NPB_BITS) * D + lane]);
    }
    __syncthreads();

    // epilogue: *W, coalesced float4 stores
    const long long node0 = (long long)b * NPB;
    for (int q = tid; q < NPB * D / 4; q += 512) {
        const int r = (q * 4) >> 6;   // local node
        const int c = (q * 4) & 63;   // feature
        const long long node = node0 + r;
        if (node < n_nodes) {
            const float4 a = *reinterpret_cast<const float4*>(&acc[r * D + c]);
            const float4 w = *reinterpret_cast<const float4*>(W + c);
            *reinterpret_cast<float4*>(out + node * D + c) =
                make_float4(a.x * w.x, a.y * w.y, a.z * w.z, a.w * w.w);
        }
    }
}

// ---------------- fallback: round-1 atomic scatter ----------------
__global__ void fallback_scatter(const float* __restrict__ feat, const float* __restrict__ W,
                                 const int* __restrict__ src, const int* __restrict__ dst,
                                 float* __restrict__ out, int n_edges) {
    const long long gid = (long long)blockIdx.x * blockDim.x + threadIdx.x;
    if (gid >= (long long)n_edges * 16) return;
    const int e = (int)(gid >> 4);
    const int t = (int)(gid & 15);
    const float4 f = *reinterpret_cast<const float4*>(feat + (long long)src[e] * D + t * 4);
    const float4 w = *reinterpret_cast<const float4*>(W + t * 4);
    float* o = out + (long long)dst[e] * D + t * 4;
    unsafeAtomicAdd(o + 0, f.x * w.x);
    unsafeAtomicAdd(o + 1, f.y * w.y);
    unsafeAtomicAdd(o + 2, f.z * w.z);
    unsafeAtomicAdd(o + 3, f.w * w.w);
}

extern "C" void kernel_launch(void* const* d_in, const int* in_sizes, int n_in,
                              void* d_out, int out_size, void* d_ws, size_t ws_size,
                              hipStream_t stream) {
    const float* feat = (const float*)d_in[0];
    const float* W    = (const float*)d_in[1];
    const int*   src  = (const int*)d_in[2];
    const int*   dst  = (const int*)d_in[3];
    float* out = (float*)d_out;

    const int n_edges = in_sizes[2];
    const int n_nodes = out_size / D;
    const int K = (n_nodes + NPB - 1) / NPB;

    // ws layout: counts[K] | base[K+1] | cursor[K] | packed[E]
    const size_t need = ((size_t)K * 3 + 1 + (size_t)n_edges) * sizeof(int);
    const bool src_fits = ((long long)n_nodes << NPB_BITS) < 0x7fffffffLL;
    if (ws_size < need || K > KMAX || !src_fits) {
        hipMemsetAsync(d_out, 0, (size_t)out_size * sizeof(float), stream);
        const long long total = (long long)n_edges * 16;
        fallback_scatter<<<(unsigned)((total + 255) / 256), 256, 0, stream>>>(
            feat, W, src, dst, out, n_edges);
        return;
    }

    int* counts = (int*)d_ws;
    int* base   = counts + K;
    int* cursor = base + K + 1;
    int* packed = cursor + K;

    hipMemsetAsync(counts, 0, (size_t)K * sizeof(int), stream);

    hist_kernel<<<512, 256, 0, stream>>>(dst, counts, n_edges, K);
    scan_kernel<<<1, 1024, 0, stream>>>(counts, base, cursor, K);
    part_kernel<<<(n_edges + 255) / 256, 256, 0, stream>>>(src, dst, cursor, packed, n_edges);
    accum_kernel<<<K, 512, 0, stream>>>(feat, W, base, packed, out, n_nodes);
}

// Round 4
// 725.577 us; speedup vs baseline: 1.4944x; 1.4944x over previous
//
#include <hip/hip_runtime.h>
#include <hip/hip_bf16.h>

// GCNConvDiagDGL: out = segment_sum( (features*W)[src], dst, N )
// N=100000, E=1600000, D=64, fp32.
//
// Round 3 -> 4:
//  * part_kernel's 1.6M per-lane cursor atomics (782 words in ~49 lines ->
//    cross-XCD same-address serialization, ~350us) replaced by block-aggregated
//    binning: LDS histogram per 4096-edge block, ONE global atomic per
//    (block,bucket) reservation (306K atomics), then run-writes (~5 consecutive
//    words) from registers.
//  * accum_kernel occupancy 38%->~full: 1024-thread blocks (16 waves, 32KB LDS
//    -> 2 blocks/CU = 32 waves/CU resident) for latency hiding on the random
//    feature gather.

#define D 64
#define NPB 128        // nodes per bucket
#define NPB_BITS 7
#define KMAX 1024      // max buckets supported by hist/scan/part LDS
#define PART_CHUNK 4096
#define PART_PER_THR 16  // PART_CHUNK / 256

// ---------------- block-wide exclusive scan helper ----------------
template <int NW>
__device__ inline int block_excl_scan(int val, int tid, int* lds_wsum, int* total) {
    const int lane = tid & 63;
    const int wid  = tid >> 6;
    int v = val;
#pragma unroll
    for (int d = 1; d < 64; d <<= 1) {
        int t = __shfl_up(v, d);
        if (lane >= d) v += t;
    }
    if (lane == 63) lds_wsum[wid] = v;
    __syncthreads();
    if (wid == 0) {
        int s = (lane < NW) ? lds_wsum[lane] : 0;
#pragma unroll
        for (int d = 1; d < NW; d <<= 1) {
            int t = __shfl_up(s, d);
            if (lane >= d) s += t;
        }
        if (lane < NW) lds_wsum[lane] = s;
    }
    __syncthreads();
    const int base = wid ? lds_wsum[wid - 1] : 0;
    *total = lds_wsum[NW - 1];
    return base + v - val;  // exclusive
}

// ---------------- 1. bucket histogram (LDS-staged) ----------------
__global__ void __launch_bounds__(256) hist_kernel(const int* __restrict__ dst,
                                                   int* __restrict__ counts,
                                                   int n_edges, int K) {
    __shared__ int h[KMAX];
    for (int i = threadIdx.x; i < K; i += 256) h[i] = 0;
    __syncthreads();
    for (int e = blockIdx.x * 256 + threadIdx.x; e < n_edges; e += gridDim.x * 256)
        atomicAdd(&h[dst[e] >> NPB_BITS], 1);
    __syncthreads();
    for (int i = threadIdx.x; i < K; i += 256)
        if (h[i]) atomicAdd(&counts[i], h[i]);
}

// ---------------- 2. scan K bucket counts (single block) ----------------
__global__ void __launch_bounds__(1024) scan_kernel(const int* __restrict__ counts,
                                                    int* __restrict__ base,
                                                    int* __restrict__ cursor, int K) {
    __shared__ int wsum[16];
    const int tid = threadIdx.x;
    const int v = (tid < K) ? counts[tid] : 0;
    int total;
    const int ex = block_excl_scan<16>(v, tid, wsum, &total);
    if (tid < K) { base[tid] = ex; cursor[tid] = ex; }
    if (tid == 0) base[K] = total;
}

// ---------------- 3. block-aggregated partition ----------------
// Each block owns PART_CHUNK edges (held in registers), histograms them over
// the K buckets in LDS, reserves per-bucket output ranges with one global
// atomic per (block,bucket), then writes packed words into its runs.
__global__ void __launch_bounds__(256) part_kernel(const int* __restrict__ src,
                                                   const int* __restrict__ dst,
                                                   int* __restrict__ cursor,
                                                   int* __restrict__ packed,
                                                   int n_edges, int K) {
    __shared__ int bh[KMAX];
    const int tid = threadIdx.x;
    const int e0  = blockIdx.x * PART_CHUNK;

    for (int i = tid; i < K; i += 256) bh[i] = 0;
    __syncthreads();

    int s[PART_PER_THR], d[PART_PER_THR];
#pragma unroll
    for (int k = 0; k < PART_PER_THR; ++k) {
        const int e = e0 + k * 256 + tid;   // coalesced
        if (e < n_edges) {
            s[k] = src[e];
            d[k] = dst[e];
            atomicAdd(&bh[d[k] >> NPB_BITS], 1);
        } else {
            d[k] = -1;
        }
    }
    __syncthreads();

    // convert block-local counts -> global write bases (one atomic each)
    for (int i = tid; i < K; i += 256) {
        const int c = bh[i];
        if (c) bh[i] = atomicAdd(&cursor[i], c);
    }
    __syncthreads();

#pragma unroll
    for (int k = 0; k < PART_PER_THR; ++k) {
        if (d[k] >= 0) {
            const int b   = d[k] >> NPB_BITS;
            const int pos = atomicAdd(&bh[b], 1);   // LDS cursor
            packed[pos] = (s[k] << NPB_BITS) | (d[k] & (NPB - 1));
        }
    }
}

// ---------------- 4. per-bucket LDS accumulate ----------------
// 16 waves / block, 2 blocks/CU resident (32KB LDS) -> 32 waves/CU.
__global__ void __launch_bounds__(1024) accum_kernel(const float* __restrict__ feat,
                                                     const float* __restrict__ W,
                                                     const int* __restrict__ base,
                                                     const int* __restrict__ packed,
                                                     float* __restrict__ out,
                                                     int n_nodes) {
    __shared__ float acc[NPB * D];  // 32 KB
    const int tid = threadIdx.x;
    for (int i = tid; i < NPB * D; i += 1024) acc[i] = 0.0f;
    __syncthreads();

    const int b   = blockIdx.x;
    const int beg = base[b];
    const int end = base[b + 1];
    const int wid  = tid >> 6;     // 0..15
    const int lane = tid & 63;

    const int cnt   = end - beg;
    const int chunk = (cnt + 15) >> 4;
    int i    = beg + wid * chunk;
    int iend = i + chunk;
    if (iend > end) iend = end;

    for (; i + 4 <= iend; i += 4) {
        const int p0 = packed[i + 0];
        const int p1 = packed[i + 1];
        const int p2 = packed[i + 2];
        const int p3 = packed[i + 3];
        const float f0 = feat[(p0 >> NPB_BITS) * D + lane];
        const float f1 = feat[(p1 >> NPB_BITS) * D + lane];
        const float f2 = feat[(p2 >> NPB_BITS) * D + lane];
        const float f3 = feat[(p3 >> NPB_BITS) * D + lane];
        atomicAdd(&acc[(p0 & (NPB - 1)) * D + lane], f0);
        atomicAdd(&acc[(p1 & (NPB - 1)) * D + lane], f1);
        atomicAdd(&acc[(p2 & (NPB - 1)) * D + lane], f2);
        atomicAdd(&acc[(p3 & (NPB - 1)) * D + lane], f3);
    }
    for (; i < iend; ++i) {
        const int p = packed[i];
        atomicAdd(&acc[(p & (NPB - 1)) * D + lane], feat[(p >> NPB_BITS) * D + lane]);
    }
    __syncthreads();

    // epilogue: *W, coalesced float4 stores
    const long long node0 = (long long)b * NPB;
    for (int q = tid; q < NPB * D / 4; q += 1024) {
        const int r = (q * 4) >> 6;   // local node
        const int c = (q * 4) & 63;   // feature
        const long long node = node0 + r;
        if (node < n_nodes) {
            const float4 a = *reinterpret_cast<const float4*>(&acc[r * D + c]);
            const float4 w = *reinterpret_cast<const float4*>(W + c);
            *reinterpret_cast<float4*>(out + node * D + c) =
                make_float4(a.x * w.x, a.y * w.y, a.z * w.z, a.w * w.w);
        }
    }
}

// ---------------- fallback: round-1 atomic scatter ----------------
__global__ void fallback_scatter(const float* __restrict__ feat, const float* __restrict__ W,
                                 const int* __restrict__ src, const int* __restrict__ dst,
                                 float* __restrict__ out, int n_edges) {
    const long long gid = (long long)blockIdx.x * blockDim.x + threadIdx.x;
    if (gid >= (long long)n_edges * 16) return;
    const int e = (int)(gid >> 4);
    const int t = (int)(gid & 15);
    const float4 f = *reinterpret_cast<const float4*>(feat + (long long)src[e] * D + t * 4);
    const float4 w = *reinterpret_cast<const float4*>(W + t * 4);
    float* o = out + (long long)dst[e] * D + t * 4;
    unsafeAtomicAdd(o + 0, f.x * w.x);
    unsafeAtomicAdd(o + 1, f.y * w.y);
    unsafeAtomicAdd(o + 2, f.z * w.z);
    unsafeAtomicAdd(o + 3, f.w * w.w);
}

extern "C" void kernel_launch(void* const* d_in, const int* in_sizes, int n_in,
                              void* d_out, int out_size, void* d_ws, size_t ws_size,
                              hipStream_t stream) {
    const float* feat = (const float*)d_in[0];
    const float* W    = (const float*)d_in[1];
    const int*   src  = (const int*)d_in[2];
    const int*   dst  = (const int*)d_in[3];
    float* out = (float*)d_out;

    const int n_edges = in_sizes[2];
    const int n_nodes = out_size / D;
    const int K = (n_nodes + NPB - 1) / NPB;

    // ws layout: counts[K] | base[K+1] | cursor[K] | packed[E]
    const size_t need = ((size_t)K * 3 + 1 + (size_t)n_edges) * sizeof(int);
    const bool src_fits = ((long long)n_nodes << NPB_BITS) < 0x7fffffffLL;
    if (ws_size < need || K > KMAX || !src_fits) {
        hipMemsetAsync(d_out, 0, (size_t)out_size * sizeof(float), stream);
        const long long total = (long long)n_edges * 16;
        fallback_scatter<<<(unsigned)((total + 255) / 256), 256, 0, stream>>>(
            feat, W, src, dst, out, n_edges);
        return;
    }

    int* counts = (int*)d_ws;
    int* base   = counts + K;
    int* cursor = base + K + 1;
    int* packed = cursor + K;

    hipMemsetAsync(counts, 0, (size_t)K * sizeof(int), stream);

    hist_kernel<<<512, 256, 0, stream>>>(dst, counts, n_edges, K);
    scan_kernel<<<1, 1024, 0, stream>>>(counts, base, cursor, K);
    part_kernel<<<(n_edges + PART_CHUNK - 1) / PART_CHUNK, 256, 0, stream>>>(
        src, dst, cursor, packed, n_edges, K);
    accum_kernel<<<K, 1024, 0, stream>>>(feat, W, base, packed, out, n_nodes);
}

// Round 5
// 723.141 us; speedup vs baseline: 1.4994x; 1.0034x over previous
//
#include <hip/hip_runtime.h>
#include <hip/hip_bf16.h>

// GCNConvDiagDGL: out = segment_sum( (features*W)[src], dst, N )
// N=100000, E=1600000, D=64, fp32.
//
// Round 4 -> 5: accum was MLP-starved (VGPR_Count=12 -> ~1 outstanding row
// gather per wave; occupancy 38->62% changed nothing). Rewritten in
// round-1 gather style: 16 threads per edge (thread = float4 chunk of the
// row), 2-edge ILP per thread -> 2048 threads/CU x 32 B in flight.
// LDS scatter-add via ds_add_f32 (8-way bank aliasing accepted; it overlaps
// with the gather). hist/scan/part unchanged from round 4.

#define D 64
#define NPB 128        // nodes per bucket
#define NPB_BITS 7
#define KMAX 1024      // max buckets supported by hist/scan/part LDS
#define PART_CHUNK 4096
#define PART_PER_THR 16  // PART_CHUNK / 256

// ---------------- block-wide exclusive scan helper ----------------
template <int NW>
__device__ inline int block_excl_scan(int val, int tid, int* lds_wsum, int* total) {
    const int lane = tid & 63;
    const int wid  = tid >> 6;
    int v = val;
#pragma unroll
    for (int d = 1; d < 64; d <<= 1) {
        int t = __shfl_up(v, d);
        if (lane >= d) v += t;
    }
    if (lane == 63) lds_wsum[wid] = v;
    __syncthreads();
    if (wid == 0) {
        int s = (lane < NW) ? lds_wsum[lane] : 0;
#pragma unroll
        for (int d = 1; d < NW; d <<= 1) {
            int t = __shfl_up(s, d);
            if (lane >= d) s += t;
        }
        if (lane < NW) lds_wsum[lane] = s;
    }
    __syncthreads();
    const int base = wid ? lds_wsum[wid - 1] : 0;
    *total = lds_wsum[NW - 1];
    return base + v - val;  // exclusive
}

// ---------------- 1. bucket histogram (LDS-staged) ----------------
__global__ void __launch_bounds__(256) hist_kernel(const int* __restrict__ dst,
                                                   int* __restrict__ counts,
                                                   int n_edges, int K) {
    __shared__ int h[KMAX];
    for (int i = threadIdx.x; i < K; i += 256) h[i] = 0;
    __syncthreads();
    for (int e = blockIdx.x * 256 + threadIdx.x; e < n_edges; e += gridDim.x * 256)
        atomicAdd(&h[dst[e] >> NPB_BITS], 1);
    __syncthreads();
    for (int i = threadIdx.x; i < K; i += 256)
        if (h[i]) atomicAdd(&counts[i], h[i]);
}

// ---------------- 2. scan K bucket counts (single block) ----------------
__global__ void __launch_bounds__(1024) scan_kernel(const int* __restrict__ counts,
                                                    int* __restrict__ base,
                                                    int* __restrict__ cursor, int K) {
    __shared__ int wsum[16];
    const int tid = threadIdx.x;
    const int v = (tid < K) ? counts[tid] : 0;
    int total;
    const int ex = block_excl_scan<16>(v, tid, wsum, &total);
    if (tid < K) { base[tid] = ex; cursor[tid] = ex; }
    if (tid == 0) base[K] = total;
}

// ---------------- 3. block-aggregated partition ----------------
__global__ void __launch_bounds__(256) part_kernel(const int* __restrict__ src,
                                                   const int* __restrict__ dst,
                                                   int* __restrict__ cursor,
                                                   int* __restrict__ packed,
                                                   int n_edges, int K) {
    __shared__ int bh[KMAX];
    const int tid = threadIdx.x;
    const int e0  = blockIdx.x * PART_CHUNK;

    for (int i = tid; i < K; i += 256) bh[i] = 0;
    __syncthreads();

    int s[PART_PER_THR], d[PART_PER_THR];
#pragma unroll
    for (int k = 0; k < PART_PER_THR; ++k) {
        const int e = e0 + k * 256 + tid;   // coalesced
        if (e < n_edges) {
            s[k] = src[e];
            d[k] = dst[e];
            atomicAdd(&bh[d[k] >> NPB_BITS], 1);
        } else {
            d[k] = -1;
        }
    }
    __syncthreads();

    // convert block-local counts -> global write bases (one atomic each)
    for (int i = tid; i < K; i += 256) {
        const int c = bh[i];
        if (c) bh[i] = atomicAdd(&cursor[i], c);
    }
    __syncthreads();

#pragma unroll
    for (int k = 0; k < PART_PER_THR; ++k) {
        if (d[k] >= 0) {
            const int b   = d[k] >> NPB_BITS;
            const int pos = atomicAdd(&bh[b], 1);   // LDS cursor
            packed[pos] = (s[k] << NPB_BITS) | (d[k] & (NPB - 1));
        }
    }
}

// ---------------- 4. per-bucket LDS accumulate (thread-per-float4) --------
// 1024 threads = 64 edge-slots x 16 chunk-lanes. Each thread: float4 feature
// load + 4 ds_add_f32. 2-edge ILP -> 32 B in flight per thread.
__global__ void __launch_bounds__(1024) accum_kernel(const float* __restrict__ feat,
                                                     const float* __restrict__ W,
                                                     const int* __restrict__ base,
                                                     const int* __restrict__ packed,
                                                     float* __restrict__ out,
                                                     int n_nodes) {
    __shared__ float acc[NPB * D];  // 32 KB
    const int tid = threadIdx.x;
    for (int i = tid; i < NPB * D; i += 1024) acc[i] = 0.0f;
    __syncthreads();

    const int b    = blockIdx.x;
    const int beg  = base[b];
    const int end  = base[b + 1];
    const int slot = tid >> 4;        // 0..63
    const int c    = (tid & 15) * 4;  // feature chunk start

    int i = beg + slot;
    for (; i + 64 < end; i += 128) {
        const int p0 = packed[i];
        const int p1 = packed[i + 64];
        const float4 f0 = *reinterpret_cast<const float4*>(feat + (p0 >> NPB_BITS) * D + c);
        const float4 f1 = *reinterpret_cast<const float4*>(feat + (p1 >> NPB_BITS) * D + c);
        float* a0 = &acc[(p0 & (NPB - 1)) * D + c];
        float* a1 = &acc[(p1 & (NPB - 1)) * D + c];
        atomicAdd(a0 + 0, f0.x);
        atomicAdd(a0 + 1, f0.y);
        atomicAdd(a0 + 2, f0.z);
        atomicAdd(a0 + 3, f0.w);
        atomicAdd(a1 + 0, f1.x);
        atomicAdd(a1 + 1, f1.y);
        atomicAdd(a1 + 2, f1.z);
        atomicAdd(a1 + 3, f1.w);
    }
    if (i < end) {
        const int p0 = packed[i];
        const float4 f0 = *reinterpret_cast<const float4*>(feat + (p0 >> NPB_BITS) * D + c);
        float* a0 = &acc[(p0 & (NPB - 1)) * D + c];
        atomicAdd(a0 + 0, f0.x);
        atomicAdd(a0 + 1, f0.y);
        atomicAdd(a0 + 2, f0.z);
        atomicAdd(a0 + 3, f0.w);
    }
    __syncthreads();

    // epilogue: *W, coalesced float4 stores
    const long long node0 = (long long)b * NPB;
    for (int q = tid; q < NPB * D / 4; q += 1024) {
        const int r = (q * 4) >> 6;   // local node
        const int cc = (q * 4) & 63;  // feature
        const long long node = node0 + r;
        if (node < n_nodes) {
            const float4 a = *reinterpret_cast<const float4*>(&acc[r * D + cc]);
            const float4 w = *reinterpret_cast<const float4*>(W + cc);
            *reinterpret_cast<float4*>(out + node * D + cc) =
                make_float4(a.x * w.x, a.y * w.y, a.z * w.z, a.w * w.w);
        }
    }
}

// ---------------- fallback: round-1 atomic scatter ----------------
__global__ void fallback_scatter(const float* __restrict__ feat, const float* __restrict__ W,
                                 const int* __restrict__ src, const int* __restrict__ dst,
                                 float* __restrict__ out, int n_edges) {
    const long long gid = (long long)blockIdx.x * blockDim.x + threadIdx.x;
    if (gid >= (long long)n_edges * 16) return;
    const int e = (int)(gid >> 4);
    const int t = (int)(gid & 15);
    const float4 f = *reinterpret_cast<const float4*>(feat + (long long)src[e] * D + t * 4);
    const float4 w = *reinterpret_cast<const float4*>(W + t * 4);
    float* o = out + (long long)dst[e] * D + t * 4;
    unsafeAtomicAdd(o + 0, f.x * w.x);
    unsafeAtomicAdd(o + 1, f.y * w.y);
    unsafeAtomicAdd(o + 2, f.z * w.z);
    unsafeAtomicAdd(o + 3, f.w * w.w);
}

extern "C" void kernel_launch(void* const* d_in, const int* in_sizes, int n_in,
                              void* d_out, int out_size, void* d_ws, size_t ws_size,
                              hipStream_t stream) {
    const float* feat = (const float*)d_in[0];
    const float* W    = (const float*)d_in[1];
    const int*   src  = (const int*)d_in[2];
    const int*   dst  = (const int*)d_in[3];
    float* out = (float*)d_out;

    const int n_edges = in_sizes[2];
    const int n_nodes = out_size / D;
    const int K = (n_nodes + NPB - 1) / NPB;

    // ws layout: counts[K] | base[K+1] | cursor[K] | packed[E]
    const size_t need = ((size_t)K * 3 + 1 + (size_t)n_edges) * sizeof(int);
    const bool src_fits = ((long long)n_nodes << NPB_BITS) < 0x7fffffffLL;
    if (ws_size < need || K > KMAX || !src_fits) {
        hipMemsetAsync(d_out, 0, (size_t)out_size * sizeof(float), stream);
        const long long total = (long long)n_edges * 16;
        fallback_scatter<<<(unsigned)((total + 255) / 256), 256, 0, stream>>>(
            feat, W, src, dst, out, n_edges);
        return;
    }

    int* counts = (int*)d_ws;
    int* base   = counts + K;
    int* cursor = base + K + 1;
    int* packed = cursor + K;

    hipMemsetAsync(counts, 0, (size_t)K * sizeof(int), stream);

    hist_kernel<<<512, 256, 0, stream>>>(dst, counts, n_edges, K);
    scan_kernel<<<1, 1024, 0, stream>>>(counts, base, cursor, K);
    part_kernel<<<(n_edges + PART_CHUNK - 1) / PART_CHUNK, 256, 0, stream>>>(
        src, dst, cursor, packed, n_edges, K);
    accum_kernel<<<K, 1024, 0, stream>>>(feat, W, base, packed, out, n_nodes);
}

// Round 6
// 117.892 us; speedup vs baseline: 9.1975x; 6.1340x over previous
//
#include <hip/hip_runtime.h>
#include <hip/hip_bf16.h>

// GCNConvDiagDGL: out = segment_sum( (features*W)[src], dst, N )
// N=100000, E=1600000, D=64, fp32.
//
// Round 5 -> 6: R3/R4/R5 accum variants were identical at ~675us; the shared
// invariant was 102.4M LDS ds_add_f32 lane-ops (~108 cyc / 64-lane atomic
// instr) -> LDS-atomic-throughput-bound. New accum removes ALL fp atomics:
//   per bucket tile (<=4096 edges): counting-sort packed words by dst_local
//   in LDS (128-bin hist + wave0 scan + LDS scatter; only cursor atomics),
//   then wave w accumulates nodes [8w,8w+8) in REGISTERS (lane=feature,
//   4-deep ILP row gather), epilogue *W[lane] + coalesced 256B stores.
// hist/scan/part unchanged from round 4.

#define D 64
#define NPB 128        // nodes per bucket
#define NPB_BITS 7
#define KMAX 1024      // max buckets supported by hist/scan/part LDS
#define PART_CHUNK 4096
#define PART_PER_THR 16  // PART_CHUNK / 256
#define TILE 4096
#define TPT 4            // TILE / 1024

// ---------------- block-wide exclusive scan helper ----------------
template <int NW>
__device__ inline int block_excl_scan(int val, int tid, int* lds_wsum, int* total) {
    const int lane = tid & 63;
    const int wid  = tid >> 6;
    int v = val;
#pragma unroll
    for (int d = 1; d < 64; d <<= 1) {
        int t = __shfl_up(v, d);
        if (lane >= d) v += t;
    }
    if (lane == 63) lds_wsum[wid] = v;
    __syncthreads();
    if (wid == 0) {
        int s = (lane < NW) ? lds_wsum[lane] : 0;
#pragma unroll
        for (int d = 1; d < NW; d <<= 1) {
            int t = __shfl_up(s, d);
            if (lane >= d) s += t;
        }
        if (lane < NW) lds_wsum[lane] = s;
    }
    __syncthreads();
    const int base = wid ? lds_wsum[wid - 1] : 0;
    *total = lds_wsum[NW - 1];
    return base + v - val;  // exclusive
}

// ---------------- 1. bucket histogram (LDS-staged) ----------------
__global__ void __launch_bounds__(256) hist_kernel(const int* __restrict__ dst,
                                                   int* __restrict__ counts,
                                                   int n_edges, int K) {
    __shared__ int h[KMAX];
    for (int i = threadIdx.x; i < K; i += 256) h[i] = 0;
    __syncthreads();
    for (int e = blockIdx.x * 256 + threadIdx.x; e < n_edges; e += gridDim.x * 256)
        atomicAdd(&h[dst[e] >> NPB_BITS], 1);
    __syncthreads();
    for (int i = threadIdx.x; i < K; i += 256)
        if (h[i]) atomicAdd(&counts[i], h[i]);
}

// ---------------- 2. scan K bucket counts (single block) ----------------
__global__ void __launch_bounds__(1024) scan_kernel(const int* __restrict__ counts,
                                                    int* __restrict__ base,
                                                    int* __restrict__ cursor, int K) {
    __shared__ int wsum[16];
    const int tid = threadIdx.x;
    const int v = (tid < K) ? counts[tid] : 0;
    int total;
    const int ex = block_excl_scan<16>(v, tid, wsum, &total);
    if (tid < K) { base[tid] = ex; cursor[tid] = ex; }
    if (tid == 0) base[K] = total;
}

// ---------------- 3. block-aggregated partition ----------------
__global__ void __launch_bounds__(256) part_kernel(const int* __restrict__ src,
                                                   const int* __restrict__ dst,
                                                   int* __restrict__ cursor,
                                                   int* __restrict__ packed,
                                                   int n_edges, int K) {
    __shared__ int bh[KMAX];
    const int tid = threadIdx.x;
    const int e0  = blockIdx.x * PART_CHUNK;

    for (int i = tid; i < K; i += 256) bh[i] = 0;
    __syncthreads();

    int s[PART_PER_THR], d[PART_PER_THR];
#pragma unroll
    for (int k = 0; k < PART_PER_THR; ++k) {
        const int e = e0 + k * 256 + tid;   // coalesced
        if (e < n_edges) {
            s[k] = src[e];
            d[k] = dst[e];
            atomicAdd(&bh[d[k] >> NPB_BITS], 1);
        } else {
            d[k] = -1;
        }
    }
    __syncthreads();

    // convert block-local counts -> global write bases (one atomic each)
    for (int i = tid; i < K; i += 256) {
        const int c = bh[i];
        if (c) bh[i] = atomicAdd(&cursor[i], c);
    }
    __syncthreads();

#pragma unroll
    for (int k = 0; k < PART_PER_THR; ++k) {
        if (d[k] >= 0) {
            const int b   = d[k] >> NPB_BITS;
            const int pos = atomicAdd(&bh[b], 1);   // LDS cursor
            packed[pos] = (s[k] << NPB_BITS) | (d[k] & (NPB - 1));
        }
    }
}

// ---------------- 4. per-bucket sort + register accumulate ----------------
// 16 waves. Per tile: counting-sort the tile's packed words by dst_local in
// LDS, then wave w register-accumulates nodes [8w, 8w+8) (lane = feature).
// Zero fp atomics; only int cursor atomics (2 x TILE per tile).
__global__ void __launch_bounds__(1024) accum_kernel(const float* __restrict__ feat,
                                                     const float* __restrict__ W,
                                                     const int* __restrict__ base,
                                                     const int* __restrict__ packed,
                                                     float* __restrict__ out,
                                                     int n_nodes) {
    __shared__ int s_sorted[TILE];       // 16 KB
    __shared__ int s_h[NPB];
    __shared__ int s_off[NPB + 1];
    __shared__ int s_cur[NPB];

    const int tid  = threadIdx.x;
    const int wid  = tid >> 6;     // 0..15
    const int lane = tid & 63;     // feature index
    const int b    = blockIdx.x;
    const int beg  = base[b];
    const int end  = base[b + 1];

    float acc[8];
#pragma unroll
    for (int n = 0; n < 8; ++n) acc[n] = 0.0f;

    for (int t0 = beg; t0 < end; t0 += TILE) {
        const int nt = min(TILE, end - t0);

        if (tid < NPB) s_h[tid] = 0;
        int w[TPT];
#pragma unroll
        for (int j = 0; j < TPT; ++j) {
            const int idx = j * 1024 + tid;          // coalesced
            w[j] = (idx < nt) ? packed[t0 + idx] : -1;
        }
        __syncthreads();

        // 128-bin histogram of dst_local
#pragma unroll
        for (int j = 0; j < TPT; ++j)
            if (w[j] >= 0) atomicAdd(&s_h[w[j] & (NPB - 1)], 1);
        __syncthreads();

        // exclusive scan of 128 bins by wave 0 (2 bins / lane)
        if (wid == 0) {
            const int a  = s_h[2 * lane];
            const int bb = s_h[2 * lane + 1];
            const int s  = a + bb;
            int incl = s;
#pragma unroll
            for (int dd = 1; dd < 64; dd <<= 1) {
                const int t = __shfl_up(incl, dd);
                if (lane >= dd) incl += t;
            }
            const int bx = incl - s;
            s_off[2 * lane]     = bx;
            s_off[2 * lane + 1] = bx + a;
            s_cur[2 * lane]     = bx;
            s_cur[2 * lane + 1] = bx + a;
            if (lane == 63) s_off[NPB] = incl;
        }
        __syncthreads();

        // scatter into node-sorted order
#pragma unroll
        for (int j = 0; j < TPT; ++j)
            if (w[j] >= 0) {
                const int r   = w[j] & (NPB - 1);
                const int pos = atomicAdd(&s_cur[r], 1);
                s_sorted[pos] = w[j];
            }
        __syncthreads();

        // register-accumulate: wave wid owns local nodes [8*wid, 8*wid+8)
#pragma unroll
        for (int n = 0; n < 8; ++n) {
            const int r  = wid * 8 + n;
            int e        = s_off[r];      // broadcast LDS reads (uniform addr)
            const int ee = s_off[r + 1];
            float a = acc[n];
            for (; e + 4 <= ee; e += 4) {
                const int w0 = s_sorted[e + 0];
                const int w1 = s_sorted[e + 1];
                const int w2 = s_sorted[e + 2];
                const int w3 = s_sorted[e + 3];
                const float f0 = feat[(w0 >> NPB_BITS) * D + lane];
                const float f1 = feat[(w1 >> NPB_BITS) * D + lane];
                const float f2 = feat[(w2 >> NPB_BITS) * D + lane];
                const float f3 = feat[(w3 >> NPB_BITS) * D + lane];
                a += (f0 + f1) + (f2 + f3);
            }
            for (; e < ee; ++e)
                a += feat[(s_sorted[e] >> NPB_BITS) * D + lane];
            acc[n] = a;
        }
        __syncthreads();   // protect LDS before next tile
    }

    // epilogue: *W, one coalesced 256B store per node
    const float wl = W[lane];
    const long long node0 = (long long)b * NPB + wid * 8;
#pragma unroll
    for (int n = 0; n < 8; ++n) {
        const long long node = node0 + n;
        if (node < n_nodes) out[node * D + lane] = acc[n] * wl;
    }
}

// ---------------- fallback: round-1 atomic scatter ----------------
__global__ void fallback_scatter(const float* __restrict__ feat, const float* __restrict__ W,
                                 const int* __restrict__ src, const int* __restrict__ dst,
                                 float* __restrict__ out, int n_edges) {
    const long long gid = (long long)blockIdx.x * blockDim.x + threadIdx.x;
    if (gid >= (long long)n_edges * 16) return;
    const int e = (int)(gid >> 4);
    const int t = (int)(gid & 15);
    const float4 f = *reinterpret_cast<const float4*>(feat + (long long)src[e] * D + t * 4);
    const float4 w = *reinterpret_cast<const float4*>(W + t * 4);
    float* o = out + (long long)dst[e] * D + t * 4;
    unsafeAtomicAdd(o + 0, f.x * w.x);
    unsafeAtomicAdd(o + 1, f.y * w.y);
    unsafeAtomicAdd(o + 2, f.z * w.z);
    unsafeAtomicAdd(o + 3, f.w * w.w);
}

extern "C" void kernel_launch(void* const* d_in, const int* in_sizes, int n_in,
                              void* d_out, int out_size, void* d_ws, size_t ws_size,
                              hipStream_t stream) {
    const float* feat = (const float*)d_in[0];
    const float* W    = (const float*)d_in[1];
    const int*   src  = (const int*)d_in[2];
    const int*   dst  = (const int*)d_in[3];
    float* out = (float*)d_out;

    const int n_edges = in_sizes[2];
    const int n_nodes = out_size / D;
    const int K = (n_nodes + NPB - 1) / NPB;

    // ws layout: counts[K] | base[K+1] | cursor[K] | packed[E]
    const size_t need = ((size_t)K * 3 + 1 + (size_t)n_edges) * sizeof(int);
    const bool src_fits = ((long long)n_nodes << NPB_BITS) < 0x7fffffffLL;
    if (ws_size < need || K > KMAX || !src_fits) {
        hipMemsetAsync(d_out, 0, (size_t)out_size * sizeof(float), stream);
        const long long total = (long long)n_edges * 16;
        fallback_scatter<<<(unsigned)((total + 255) / 256), 256, 0, stream>>>(
            feat, W, src, dst, out, n_edges);
        return;
    }

    int* counts = (int*)d_ws;
    int* base   = counts + K;
    int* cursor = base + K + 1;
    int* packed = cursor + K;

    hipMemsetAsync(counts, 0, (size_t)K * sizeof(int), stream);

    hist_kernel<<<512, 256, 0, stream>>>(dst, counts, n_edges, K);
    scan_kernel<<<1, 1024, 0, stream>>>(counts, base, cursor, K);
    part_kernel<<<(n_edges + PART_CHUNK - 1) / PART_CHUNK, 256, 0, stream>>>(
        src, dst, cursor, packed, n_edges, K);
    accum_kernel<<<K, 1024, 0, stream>>>(feat, W, base, packed, out, n_nodes);
}

// Round 7
// 101.550 us; speedup vs baseline: 10.6777x; 1.1609x over previous
//
#include <hip/hip_runtime.h>
#include <hip/hip_bf16.h>

// GCNConvDiagDGL: out = segment_sum( (features*W)[src], dst, N )
// N=100000, E=1600000, D=64, fp32.
//
// Round 6 -> 7:
//  * accum: 1024-thr blocks (2/CU resident, K=782 grid -> 1.53 rounds, ~24%
//    tail idle, Occ 62%) -> 512-thr blocks (8 waves x 16 nodes, acc[16],
//    4 blocks/CU -> all 782 co-resident). Staging registers dropped (packed[]
//    re-read from L2 in scatter pass) to stay <=64 VGPR.
//  * hist/part: int4-vectorized index loads; hist 256 blocks (halve flush
//    atomics); part chunk 8192 @ 512 thr (halve reservation atomics).

#define D 64
#define NPB 128        // nodes per bucket
#define NPB_BITS 7
#define KMAX 1024      // max buckets supported by hist/scan/part LDS
#define PART_CHUNK 8192
#define TILE 4096
#define TPT 8            // TILE / 512

// ---------------- block-wide exclusive scan helper ----------------
template <int NW>
__device__ inline int block_excl_scan(int val, int tid, int* lds_wsum, int* total) {
    const int lane = tid & 63;
    const int wid  = tid >> 6;
    int v = val;
#pragma unroll
    for (int d = 1; d < 64; d <<= 1) {
        int t = __shfl_up(v, d);
        if (lane >= d) v += t;
    }
    if (lane == 63) lds_wsum[wid] = v;
    __syncthreads();
    if (wid == 0) {
        int s = (lane < NW) ? lds_wsum[lane] : 0;
#pragma unroll
        for (int d = 1; d < NW; d <<= 1) {
            int t = __shfl_up(s, d);
            if (lane >= d) s += t;
        }
        if (lane < NW) lds_wsum[lane] = s;
    }
    __syncthreads();
    const int base = wid ? lds_wsum[wid - 1] : 0;
    *total = lds_wsum[NW - 1];
    return base + v - val;  // exclusive
}

// ---------------- 1. bucket histogram (LDS-staged, int4 loads) -----------
__global__ void __launch_bounds__(512) hist_kernel(const int* __restrict__ dst,
                                                   int* __restrict__ counts,
                                                   int n_edges, int K) {
    __shared__ int h[KMAX];
    for (int i = threadIdx.x; i < K; i += 512) h[i] = 0;
    __syncthreads();
    const int n4 = n_edges >> 2;
    for (int i = blockIdx.x * 512 + threadIdx.x; i < n4; i += gridDim.x * 512) {
        const int4 dv = *reinterpret_cast<const int4*>(dst + (long long)i * 4);
        atomicAdd(&h[dv.x >> NPB_BITS], 1);
        atomicAdd(&h[dv.y >> NPB_BITS], 1);
        atomicAdd(&h[dv.z >> NPB_BITS], 1);
        atomicAdd(&h[dv.w >> NPB_BITS], 1);
    }
    for (int e = (n4 << 2) + blockIdx.x * 512 + threadIdx.x; e < n_edges;
         e += gridDim.x * 512)
        atomicAdd(&h[dst[e] >> NPB_BITS], 1);
    __syncthreads();
    for (int i = threadIdx.x; i < K; i += 512)
        if (h[i]) atomicAdd(&counts[i], h[i]);
}

// ---------------- 2. scan K bucket counts (single block) ----------------
__global__ void __launch_bounds__(1024) scan_kernel(const int* __restrict__ counts,
                                                    int* __restrict__ base,
                                                    int* __restrict__ cursor, int K) {
    __shared__ int wsum[16];
    const int tid = threadIdx.x;
    const int v = (tid < K) ? counts[tid] : 0;
    int total;
    const int ex = block_excl_scan<16>(v, tid, wsum, &total);
    if (tid < K) { base[tid] = ex; cursor[tid] = ex; }
    if (tid == 0) base[K] = total;
}

// ---------------- 3. block-aggregated partition (int4 loads) -------------
__global__ void __launch_bounds__(512) part_kernel(const int* __restrict__ src,
                                                   const int* __restrict__ dst,
                                                   int* __restrict__ cursor,
                                                   int* __restrict__ packed,
                                                   int n_edges, int K) {
    __shared__ int bh[KMAX];
    const int tid = threadIdx.x;
    const long long e0 = (long long)blockIdx.x * PART_CHUNK;

    for (int i = tid; i < K; i += 512) bh[i] = 0;
    __syncthreads();

    int s[16], d[16];
#pragma unroll
    for (int j = 0; j < 4; ++j) {
        const long long base = e0 + ((long long)j * 512 + tid) * 4;
        if (base + 4 <= n_edges) {
            const int4 sv = *reinterpret_cast<const int4*>(src + base);
            const int4 dv = *reinterpret_cast<const int4*>(dst + base);
            s[j * 4 + 0] = sv.x; d[j * 4 + 0] = dv.x;
            s[j * 4 + 1] = sv.y; d[j * 4 + 1] = dv.y;
            s[j * 4 + 2] = sv.z; d[j * 4 + 2] = dv.z;
            s[j * 4 + 3] = sv.w; d[j * 4 + 3] = dv.w;
            atomicAdd(&bh[dv.x >> NPB_BITS], 1);
            atomicAdd(&bh[dv.y >> NPB_BITS], 1);
            atomicAdd(&bh[dv.z >> NPB_BITS], 1);
            atomicAdd(&bh[dv.w >> NPB_BITS], 1);
        } else {
#pragma unroll
            for (int c = 0; c < 4; ++c) {
                const long long e = base + c;
                if (e < n_edges) {
                    s[j * 4 + c] = src[e];
                    d[j * 4 + c] = dst[e];
                    atomicAdd(&bh[d[j * 4 + c] >> NPB_BITS], 1);
                } else {
                    d[j * 4 + c] = -1;
                }
            }
        }
    }
    __syncthreads();

    // convert block-local counts -> global write bases (one atomic each)
    for (int i = tid; i < K; i += 512) {
        const int c = bh[i];
        if (c) bh[i] = atomicAdd(&cursor[i], c);
    }
    __syncthreads();

#pragma unroll
    for (int k = 0; k < 16; ++k) {
        if (d[k] >= 0) {
            const int b   = d[k] >> NPB_BITS;
            const int pos = atomicAdd(&bh[b], 1);   // LDS cursor
            packed[pos] = (s[k] << NPB_BITS) | (d[k] & (NPB - 1));
        }
    }
}

// ---------------- 4. per-bucket sort + register accumulate ----------------
// 512 threads = 8 waves; wave w owns local nodes [16w, 16w+16) in registers.
// packed[] is read twice per tile (hist pass + scatter pass; 2nd read L2-hot)
// to avoid register staging -> VGPR <= 64 -> 4 blocks/CU, all K co-resident.
__global__ void __launch_bounds__(512, 8) accum_kernel(const float* __restrict__ feat,
                                                       const float* __restrict__ W,
                                                       const int* __restrict__ base,
                                                       const int* __restrict__ packed,
                                                       float* __restrict__ out,
                                                       int n_nodes) {
    __shared__ int s_sorted[TILE];       // 16 KB
    __shared__ int s_h[NPB];
    __shared__ int s_off[NPB + 1];
    __shared__ int s_cur[NPB];

    const int tid  = threadIdx.x;
    const int wid  = tid >> 6;     // 0..7
    const int lane = tid & 63;     // feature index
    const int b    = blockIdx.x;
    const int beg  = base[b];
    const int end  = base[b + 1];

    float acc[16];
#pragma unroll
    for (int n = 0; n < 16; ++n) acc[n] = 0.0f;

    for (int t0 = beg; t0 < end; t0 += TILE) {
        const int nt = min(TILE, end - t0);

        if (tid < NPB) s_h[tid] = 0;
        __syncthreads();

        // 128-bin histogram of dst_local
#pragma unroll
        for (int j = 0; j < TPT; ++j) {
            const int idx = j * 512 + tid;          // coalesced
            if (idx < nt) atomicAdd(&s_h[packed[t0 + idx] & (NPB - 1)], 1);
        }
        __syncthreads();

        // exclusive scan of 128 bins by wave 0 (2 bins / lane)
        if (wid == 0) {
            const int a  = s_h[2 * lane];
            const int bb = s_h[2 * lane + 1];
            const int s  = a + bb;
            int incl = s;
#pragma unroll
            for (int dd = 1; dd < 64; dd <<= 1) {
                const int t = __shfl_up(incl, dd);
                if (lane >= dd) incl += t;
            }
            const int bx = incl - s;
            s_off[2 * lane]     = bx;
            s_off[2 * lane + 1] = bx + a;
            s_cur[2 * lane]     = bx;
            s_cur[2 * lane + 1] = bx + a;
            if (lane == 63) s_off[NPB] = incl;
        }
        __syncthreads();

        // scatter into node-sorted order (packed re-read; L2-hot)
#pragma unroll
        for (int j = 0; j < TPT; ++j) {
            const int idx = j * 512 + tid;
            if (idx < nt) {
                const int w   = packed[t0 + idx];
                const int pos = atomicAdd(&s_cur[w & (NPB - 1)], 1);
                s_sorted[pos] = w;
            }
        }
        __syncthreads();

        // register-accumulate: wave wid owns local nodes [16*wid, 16*wid+16)
#pragma unroll
        for (int n = 0; n < 16; ++n) {
            const int r  = wid * 16 + n;
            int e        = s_off[r];      // broadcast LDS reads (uniform addr)
            const int ee = s_off[r + 1];
            float a = acc[n];
            for (; e + 4 <= ee; e += 4) {
                const int w0 = s_sorted[e + 0];
                const int w1 = s_sorted[e + 1];
                const int w2 = s_sorted[e + 2];
                const int w3 = s_sorted[e + 3];
                const float f0 = feat[(w0 >> NPB_BITS) * D + lane];
                const float f1 = feat[(w1 >> NPB_BITS) * D + lane];
                const float f2 = feat[(w2 >> NPB_BITS) * D + lane];
                const float f3 = feat[(w3 >> NPB_BITS) * D + lane];
                a += (f0 + f1) + (f2 + f3);
            }
            for (; e < ee; ++e)
                a += feat[(s_sorted[e] >> NPB_BITS) * D + lane];
            acc[n] = a;
        }
        __syncthreads();   // protect LDS before next tile
    }

    // epilogue: *W, one coalesced 256B store per node
    const float wl = W[lane];
    const long long node0 = (long long)b * NPB + wid * 16;
#pragma unroll
    for (int n = 0; n < 16; ++n) {
        const long long node = node0 + n;
        if (node < n_nodes) out[node * D + lane] = acc[n] * wl;
    }
}

// ---------------- fallback: round-1 atomic scatter ----------------
__global__ void fallback_scatter(const float* __restrict__ feat, const float* __restrict__ W,
                                 const int* __restrict__ src, const int* __restrict__ dst,
                                 float* __restrict__ out, int n_edges) {
    const long long gid = (long long)blockIdx.x * blockDim.x + threadIdx.x;
    if (gid >= (long long)n_edges * 16) return;
    const int e = (int)(gid >> 4);
    const int t = (int)(gid & 15);
    const float4 f = *reinterpret_cast<const float4*>(feat + (long long)src[e] * D + t * 4);
    const float4 w = *reinterpret_cast<const float4*>(W + t * 4);
    float* o = out + (long long)dst[e] * D + t * 4;
    unsafeAtomicAdd(o + 0, f.x * w.x);
    unsafeAtomicAdd(o + 1, f.y * w.y);
    unsafeAtomicAdd(o + 2, f.z * w.z);
    unsafeAtomicAdd(o + 3, f.w * w.w);
}

extern "C" void kernel_launch(void* const* d_in, const int* in_sizes, int n_in,
                              void* d_out, int out_size, void* d_ws, size_t ws_size,
                              hipStream_t stream) {
    const float* feat = (const float*)d_in[0];
    const float* W    = (const float*)d_in[1];
    const int*   src  = (const int*)d_in[2];
    const int*   dst  = (const int*)d_in[3];
    float* out = (float*)d_out;

    const int n_edges = in_sizes[2];
    const int n_nodes = out_size / D;
    const int K = (n_nodes + NPB - 1) / NPB;

    // ws layout: counts[K] | base[K+1] | cursor[K] | packed[E]
    const size_t need = ((size_t)K * 3 + 1 + (size_t)n_edges) * sizeof(int);
    const bool src_fits = ((long long)n_nodes << NPB_BITS) < 0x7fffffffLL;
    if (ws_size < need || K > KMAX || !src_fits) {
        hipMemsetAsync(d_out, 0, (size_t)out_size * sizeof(float), stream);
        const long long total = (long long)n_edges * 16;
        fallback_scatter<<<(unsigned)((total + 255) / 256), 256, 0, stream>>>(
            feat, W, src, dst, out, n_edges);
        return;
    }

    int* counts = (int*)d_ws;
    int* base   = counts + K;
    int* cursor = base + K + 1;
    int* packed = cursor + K;

    hipMemsetAsync(counts, 0, (size_t)K * sizeof(int), stream);

    hist_kernel<<<256, 512, 0, stream>>>(dst, counts, n_edges, K);
    scan_kernel<<<1, 1024, 0, stream>>>(counts, base, cursor, K);
    part_kernel<<<(n_edges + PART_CHUNK - 1) / PART_CHUNK, 512, 0, stream>>>(
        src, dst, cursor, packed, n_edges, K);
    accum_kernel<<<K, 512, 0, stream>>>(feat, W, base, packed, out, n_nodes);
}